// Round 3
// baseline (42.306 us; speedup 1.0000x reference)
//
#include <hip/hip_runtime.h>
#include <math.h>

#define NUM_EXPERTS 64
#define TOP_K 6
#define HIDDEN 2048
#define INTER 1024

// ---------------- Kernel 1: gate logits (one block per expert) ----------------
__global__ __launch_bounds__(256) void k_gate(const float* __restrict__ gw,
                                              const float* __restrict__ x,
                                              float* __restrict__ logits) {
    int e = blockIdx.x;
    int t = threadIdx.x;                       // 256 threads
    const float4* r4 = (const float4*)(gw + (size_t)e * HIDDEN);
    const float4* x4 = (const float4*)x;
    float sum = 0.f;
    #pragma unroll
    for (int i = t; i < HIDDEN / 4; i += 256) {
        float4 a = r4[i], b = x4[i];
        sum += a.x * b.x + a.y * b.y + a.z * b.z + a.w * b.w;
    }
    #pragma unroll
    for (int o = 32; o; o >>= 1) sum += __shfl_down(sum, o, 64);
    __shared__ float ls[4];
    if ((t & 63) == 0) ls[t >> 6] = sum;
    __syncthreads();
    if (t == 0) logits[e] = ls[0] + ls[1] + ls[2] + ls[3];
}

// ---------------- Inline wave-parallel top-6 (all-register, ~300 cyc) ----------------
// Each wave computes the full top-6 redundantly from logits/bias (L2-hot, 512 B).
// id[]/sel[] are written with compile-time-unrolled k -> stay in registers.
__device__ __forceinline__ void topk_inline(const float* __restrict__ logits,
                                            const float* __restrict__ bias,
                                            int lane, int* id, float* sel) {
    float lg = logits[lane];
    float sc = 1.0f / (1.0f + expf(-lg));      // unbiased score (gate weight)
    float cur = sc + bias[lane];               // biased score (routing key)
    #pragma unroll
    for (int k = 0; k < TOP_K; k++) {
        float v = cur; int li = lane;
        #pragma unroll
        for (int o = 32; o; o >>= 1) {
            float ov = __shfl_down(v, o, 64);
            int   oi = __shfl_down(li, o, 64);
            if (ov > v || (ov == v && oi < li)) { v = ov; li = oi; }
        }
        li = __shfl(li, 0, 64);                // broadcast winner
        id[k]  = li;
        sel[k] = __shfl(sc, li, 64);
        if (lane == li) cur = -1e30f;
    }
}

// ---------------- Kernel 2: h[k][i] = silu(w1[e_k][i].x) * (w3[e_k][i].x) ----------------
// one wave per inter-row; grid = TOP_K*INTER/4 blocks of 256 (4 waves). x staged in LDS.
__global__ __launch_bounds__(256) void k_mlp1(const float* __restrict__ w1,
                                              const float* __restrict__ w3,
                                              const float* __restrict__ x,
                                              const float* __restrict__ logits,
                                              const float* __restrict__ bias,
                                              float* __restrict__ hbuf) {
    __shared__ float4 xs[HIDDEN / 4];          // 8 KB
    int t = threadIdx.x;
    const float4* x4 = (const float4*)x;
    #pragma unroll
    for (int i = t; i < HIDDEN / 4; i += 256) xs[i] = x4[i];
    __syncthreads();

    int wave = t >> 6;
    int lane = t & 63;
    int g = blockIdx.x * 4 + wave;             // [0, TOP_K*INTER)
    int k = g >> 10;                           // / INTER
    int i = g & (INTER - 1);

    int id[TOP_K]; float sel[TOP_K];
    topk_inline(logits, bias, lane, id, sel);
    int e = id[0];
    #pragma unroll
    for (int kk = 1; kk < TOP_K; kk++) if (kk == k) e = id[kk];  // cndmask chain, no scratch

    float4 xr[8];
    #pragma unroll
    for (int j = 0; j < 8; j++) xr[j] = xs[lane + 64 * j];

    const float4* a4 = (const float4*)(w1 + ((size_t)e * INTER + i) * HIDDEN);
    const float4* b4 = (const float4*)(w3 + ((size_t)e * INTER + i) * HIDDEN);
    float sg = 0.f, su = 0.f;
    #pragma unroll
    for (int j = 0; j < 8; j++) {
        float4 a = a4[lane + 64 * j];
        sg += a.x * xr[j].x + a.y * xr[j].y + a.z * xr[j].z + a.w * xr[j].w;
        float4 b = b4[lane + 64 * j];
        su += b.x * xr[j].x + b.y * xr[j].y + b.z * xr[j].z + b.w * xr[j].w;
    }
    #pragma unroll
    for (int o = 32; o; o >>= 1) {
        sg += __shfl_down(sg, o, 64);
        su += __shfl_down(su, o, 64);
    }
    if (lane == 0) {
        float gate = sg / (1.0f + expf(-sg));   // silu
        hbuf[k * INTER + i] = gate * su;
    }
}

// ---------------- Kernel 3: out[h] = sum_k w[k] * dot(w2[e_k][h], h_k) ----------------
// one wave per output element; grid = HIDDEN/4 blocks of 256 (4 waves).
// hbuf (24 KB) staged in LDS per block; topk + weight-norm inlined per wave.
__global__ __launch_bounds__(256) void k_mlp2(const float* __restrict__ w2,
                                              const float* __restrict__ logits,
                                              const float* __restrict__ bias,
                                              const float* __restrict__ hbuf,
                                              float* __restrict__ out) {
    __shared__ float4 hs[TOP_K * INTER / 4];   // 24 KB
    int t = threadIdx.x;
    const float4* h4 = (const float4*)hbuf;
    #pragma unroll
    for (int i = t; i < TOP_K * INTER / 4; i += 256) hs[i] = h4[i];
    __syncthreads();

    int wave = t >> 6;
    int lane = t & 63;
    int h = blockIdx.x * 4 + wave;             // [0, HIDDEN)

    int id[TOP_K]; float sel[TOP_K];
    topk_inline(logits, bias, lane, id, sel);
    float inv = 1.0f / (sel[0] + sel[1] + sel[2] + sel[3] + sel[4] + sel[5] + 1e-20f);

    float acc = 0.f;
    #pragma unroll
    for (int k = 0; k < TOP_K; k++) {
        int e = id[k];
        const float4* r4 = (const float4*)(w2 + ((size_t)e * HIDDEN + h) * INTER);
        float s = 0.f;
        #pragma unroll
        for (int j = 0; j < 4; j++) {
            float4 a = r4[lane + 64 * j];
            float4 b = hs[k * (INTER / 4) + lane + 64 * j];
            s += a.x * b.x + a.y * b.y + a.z * b.z + a.w * b.w;
        }
        acc += (sel[k] * inv) * s;
    }
    #pragma unroll
    for (int o = 32; o; o >>= 1) acc += __shfl_down(acc, o, 64);
    if (lane == 0) out[h] = acc;
}

extern "C" void kernel_launch(void* const* d_in, const int* in_sizes, int n_in,
                              void* d_out, int out_size, void* d_ws, size_t ws_size,
                              hipStream_t stream) {
    const float* x    = (const float*)d_in[0];
    const float* gw   = (const float*)d_in[1];
    const float* bias = (const float*)d_in[2];
    const float* w1   = (const float*)d_in[3];
    const float* w2   = (const float*)d_in[4];
    const float* w3   = (const float*)d_in[5];
    float* out = (float*)d_out;

    float* ws_f   = (float*)d_ws;
    float* logits = ws_f;                       // 64 floats
    float* hbuf   = ws_f + 128;                 // TOP_K*INTER = 6144 floats

    k_gate<<<NUM_EXPERTS, 256, 0, stream>>>(gw, x, logits);
    k_mlp1<<<TOP_K * INTER / 4, 256, 0, stream>>>(w1, w3, x, logits, bias, hbuf);
    k_mlp2<<<HIDDEN / 4, 256, 0, stream>>>(w2, logits, bias, hbuf, out);
}